// Round 7
// baseline (175.025 us; speedup 1.0000x reference)
//
#include <hip/hip_runtime.h>
#include <hip/hip_bf16.h>

#define L_SEQ    1024
#define IN_DIM   256
#define DIM_MSA  32
#define PAIR_DIM 64
#define ISPLIT   8
#define ICHUNK   (L_SEQ / ISPLIT)   // 128

// s[i][c] = b1[c] + sum_d seq[i][d] * W1[c][d]
__global__ void k_proj1(const float* __restrict__ seq, const float* __restrict__ W1,
                        const float* __restrict__ b1, float* __restrict__ s) {
    int t = blockIdx.x * blockDim.x + threadIdx.x;   // 1024*32 threads
    int i = t >> 5, c = t & 31;
    const float4* sq = (const float4*)(seq + i * IN_DIM);
    const float4* w  = (const float4*)(W1  + c * IN_DIM);
    float a0 = 0.f, a1 = 0.f, a2 = 0.f, a3 = 0.f;
#pragma unroll
    for (int d4 = 0; d4 < IN_DIM / 4; ++d4) {
        float4 x = sq[d4], y = w[d4];
        a0 += x.x * y.x;  a1 += x.y * y.y;
        a2 += x.z * y.z;  a3 += x.w * y.w;
    }
    s[t] = b1[c] + ((a0 + a1) + (a2 + a3));
}

// tmp[j][p][d] = sum_c s[j][c] * W2[p][c*32+d]   (thread computes 4 consecutive d)
__global__ void k_proj2(const float* __restrict__ s, const float* __restrict__ W2,
                        float* __restrict__ tmp) {
    int t = blockIdx.x * blockDim.x + threadIdx.x;   // 1024*64*8 threads
    int q = t & 7, p = (t >> 3) & 63, j = t >> 9;
    const float4* w  = (const float4*)W2;            // idx = p*256 + c*8 + q
    const float*  sj = s + j * DIM_MSA;
    float4 acc = {0.f, 0.f, 0.f, 0.f};
#pragma unroll
    for (int c = 0; c < DIM_MSA; ++c) {
        float  sc = sj[c];
        float4 wv = w[p * 256 + c * 8 + q];
        acc.x += sc * wv.x;  acc.y += sc * wv.y;
        acc.z += sc * wv.z;  acc.w += sc * wv.w;
    }
    ((float4*)tmp)[t] = acc;   // t = j*512 + p*8 + q  ==  [j][p][d] as float4
}

// out[i][j][p] = sum_d s[i][d]*tmp[j][p][d] + b2[p] + pair[i][j][p]
// R2-proven residency shape: one wave per (j, i-chunk), lane = p.
// tmp[j][lane][0..31] in 8 NAMED float4 (32 VGPRs, stays resident at 8 waves/EU).
// s[i,:] is wave-uniform -> scalar loads (SGPRs via K$), NO LDS, no barriers.
__global__ __launch_bounds__(256) void k_outer(
    const float* __restrict__ s, const float* __restrict__ tmp,
    const float* __restrict__ pair, const float* __restrict__ b2,
    float* __restrict__ out) {
    int tid  = threadIdx.x;
    int wave = tid >> 6, lane = tid & 63;
    int jgrp  = blockIdx.x & 255;               // 256 j-groups of 4
    int chunk = blockIdx.x >> 8;                // ISPLIT i-chunks
    int j  = jgrp * 4 + wave;
    int i0 = chunk * ICHUNK;

    // tmp[j][lane][0..31] -> 8 named float4 (proven resident in R2)
    const float4* tj = (const float4*)(tmp + (size_t)(j * PAIR_DIM + lane) * DIM_MSA);
    float4 r0 = tj[0], r1 = tj[1], r2 = tj[2], r3 = tj[3],
           r4 = tj[4], r5 = tj[5], r6 = tj[6], r7 = tj[7];
    float bias = b2[lane];

    const size_t stride = (size_t)L_SEQ * PAIR_DIM;              // 65536
    const float* pr = pair + ((size_t)i0 * L_SEQ + j) * PAIR_DIM + lane;
    float*       po = out  + ((size_t)i0 * L_SEQ + j) * PAIR_DIM + lane;

    float A  = pr[0];                                            // i0
    float Bv = pr[stride];                                       // i0+1
    pr += 2 * stride;                                            // -> i0+2

#pragma unroll 2
    for (int it = 0; it < ICHUNK - 2; ++it) {
        float Cv = *pr;  pr += stride;                           // prefetch it+2
        // s[i0+it][0..31] — wave-uniform -> SMEM scalar loads
        const float4* sg = (const float4*)(s + (size_t)(i0 + it) * DIM_MSA);
        float4 s0 = sg[0], s1 = sg[1], s2 = sg[2], s3 = sg[3],
               s4 = sg[4], s5 = sg[5], s6 = sg[6], s7 = sg[7];
        float a0 = s0.x*r0.x + s0.y*r0.y + s0.z*r0.z + s0.w*r0.w
                 + s1.x*r1.x + s1.y*r1.y + s1.z*r1.z + s1.w*r1.w;
        float a1 = s2.x*r2.x + s2.y*r2.y + s2.z*r2.z + s2.w*r2.w
                 + s3.x*r3.x + s3.y*r3.y + s3.z*r3.z + s3.w*r3.w;
        float a2 = s4.x*r4.x + s4.y*r4.y + s4.z*r4.z + s4.w*r4.w
                 + s5.x*r5.x + s5.y*r5.y + s5.z*r5.z + s5.w*r5.w;
        float a3 = s6.x*r6.x + s6.y*r6.y + s6.z*r6.z + s6.w*r6.w
                 + s7.x*r7.x + s7.y*r7.y + s7.z*r7.z + s7.w*r7.w;
        __builtin_nontemporal_store(((a0 + a1) + (a2 + a3)) + bias + A, po);
        po += stride;
        A = Bv;  Bv = Cv;
    }
#pragma unroll
    for (int t2 = 0; t2 < 2; ++t2) {                             // peeled last two
        int it = ICHUNK - 2 + t2;
        const float4* sg = (const float4*)(s + (size_t)(i0 + it) * DIM_MSA);
        float4 s0 = sg[0], s1 = sg[1], s2 = sg[2], s3 = sg[3],
               s4 = sg[4], s5 = sg[5], s6 = sg[6], s7 = sg[7];
        float a0 = s0.x*r0.x + s0.y*r0.y + s0.z*r0.z + s0.w*r0.w
                 + s1.x*r1.x + s1.y*r1.y + s1.z*r1.z + s1.w*r1.w;
        float a1 = s2.x*r2.x + s2.y*r2.y + s2.z*r2.z + s2.w*r2.w
                 + s3.x*r3.x + s3.y*r3.y + s3.z*r3.z + s3.w*r3.w;
        float a2 = s4.x*r4.x + s4.y*r4.y + s4.z*r4.z + s4.w*r4.w
                 + s5.x*r5.x + s5.y*r5.y + s5.z*r5.z + s5.w*r5.w;
        float a3 = s6.x*r6.x + s6.y*r6.y + s6.z*r6.z + s6.w*r6.w
                 + s7.x*r7.x + s7.y*r7.y + s7.z*r7.z + s7.w*r7.w;
        __builtin_nontemporal_store(((a0 + a1) + (a2 + a3)) + bias + A, po);
        po += stride;
        A = Bv;
    }
}

extern "C" void kernel_launch(void* const* d_in, const int* in_sizes, int n_in,
                              void* d_out, int out_size, void* d_ws, size_t ws_size,
                              hipStream_t stream) {
    const float* seq  = (const float*)d_in[0];   // [1,1024,256]
    const float* pair = (const float*)d_in[1];   // [1,1024,1024,64]
    const float* W1   = (const float*)d_in[2];   // [32,256]
    const float* b1   = (const float*)d_in[3];   // [32]
    const float* W2   = (const float*)d_in[4];   // [64,1024]
    const float* b2   = (const float*)d_in[5];   // [64]
    float* out = (float*)d_out;

    float* s_ws   = (float*)d_ws;                         // 1024*32   = 128 KB
    float* tmp_ws = s_ws + (size_t)L_SEQ * DIM_MSA;       // 1024*64*32 = 8 MB

    k_proj1<<<(L_SEQ * DIM_MSA) / 256, 256, 0, stream>>>(seq, W1, b1, s_ws);
    k_proj2<<<(L_SEQ * PAIR_DIM * (DIM_MSA / 4)) / 256, 256, 0, stream>>>(s_ws, W2, tmp_ws);
    k_outer<<<256 * ISPLIT, 256, 0, stream>>>(s_ws, tmp_ws, pair, b2, out);
}

// Round 8
// 137.212 us; speedup vs baseline: 1.2756x; 1.2756x over previous
//
#include <hip/hip_runtime.h>
#include <hip/hip_bf16.h>

#define L_SEQ    1024
#define IN_DIM   256
#define DIM_MSA  32
#define PAIR_DIM 64
#define ISPLIT   8
#define ICHUNK   (L_SEQ / ISPLIT)   // 128
#define GRP      8                  // prefetch distance (named rotating regs)

// s[i][c] = b1[c] + sum_d seq[i][d] * W1[c][d]
__global__ void k_proj1(const float* __restrict__ seq, const float* __restrict__ W1,
                        const float* __restrict__ b1, float* __restrict__ s) {
    int t = blockIdx.x * blockDim.x + threadIdx.x;   // 1024*32 threads
    int i = t >> 5, c = t & 31;
    const float4* sq = (const float4*)(seq + i * IN_DIM);
    const float4* w  = (const float4*)(W1  + c * IN_DIM);
    float a0 = 0.f, a1 = 0.f, a2 = 0.f, a3 = 0.f;
#pragma unroll
    for (int d4 = 0; d4 < IN_DIM / 4; ++d4) {
        float4 x = sq[d4], y = w[d4];
        a0 += x.x * y.x;  a1 += x.y * y.y;
        a2 += x.z * y.z;  a3 += x.w * y.w;
    }
    s[t] = b1[c] + ((a0 + a1) + (a2 + a3));
}

// tmp[j][p][d] = sum_c s[j][c] * W2[p][c*32+d]   (thread computes 4 consecutive d)
__global__ void k_proj2(const float* __restrict__ s, const float* __restrict__ W2,
                        float* __restrict__ tmp) {
    int t = blockIdx.x * blockDim.x + threadIdx.x;   // 1024*64*8 threads
    int q = t & 7, p = (t >> 3) & 63, j = t >> 9;
    const float4* w  = (const float4*)W2;            // idx = p*256 + c*8 + q
    const float*  sj = s + j * DIM_MSA;
    float4 acc = {0.f, 0.f, 0.f, 0.f};
#pragma unroll
    for (int c = 0; c < DIM_MSA; ++c) {
        float  sc = sj[c];
        float4 wv = w[p * 256 + c * 8 + q];
        acc.x += sc * wv.x;  acc.y += sc * wv.y;
        acc.z += sc * wv.z;  acc.w += sc * wv.w;
    }
    ((float4*)tmp)[t] = acc;   // t = j*512 + p*8 + q  ==  [j][p][d] as float4
}

__device__ __forceinline__ float dot32(const float* __restrict__ srow,
    const float4 r0, const float4 r1, const float4 r2, const float4 r3,
    const float4 r4, const float4 r5, const float4 r6, const float4 r7) {
    const float4* sg = (const float4*)srow;           // wave-uniform -> s_load
    float4 s0 = sg[0], s1 = sg[1], s2 = sg[2], s3 = sg[3],
           s4 = sg[4], s5 = sg[5], s6 = sg[6], s7 = sg[7];
    float a0 = s0.x*r0.x + s0.y*r0.y + s0.z*r0.z + s0.w*r0.w
             + s1.x*r1.x + s1.y*r1.y + s1.z*r1.z + s1.w*r1.w;
    float a1 = s2.x*r2.x + s2.y*r2.y + s2.z*r2.z + s2.w*r2.w
             + s3.x*r3.x + s3.y*r3.y + s3.z*r3.z + s3.w*r3.w;
    float a2 = s4.x*r4.x + s4.y*r4.y + s4.z*r4.z + s4.w*r4.w
             + s5.x*r5.x + s5.y*r5.y + s5.z*r5.z + s5.w*r5.w;
    float a3 = s6.x*r6.x + s6.y*r6.y + s6.z*r6.z + s6.w*r6.w
             + s7.x*r7.x + s7.y*r7.y + s7.z*r7.z + s7.w*r7.w;
    return (a0 + a1) + (a2 + a3);
}

// out[i][j][p] = sum_d s[i][d]*tmp[j][p][d] + b2[p] + pair[i][j][p]
// One wave per (j, i-chunk), lane = p. 8 named float4 frags (proven resident).
// s[i,:] wave-uniform -> SGPR scalar loads. Pair loads: depth-8 rotating
// prefetch (pv0..pv7) to put 2 KB/wave in flight -> break the Little's-law
// ceiling at ~2.4 TB/s.
__global__ __launch_bounds__(256) void k_outer(
    const float* __restrict__ s, const float* __restrict__ tmp,
    const float* __restrict__ pair, const float* __restrict__ b2,
    float* __restrict__ out) {
    int tid  = threadIdx.x;
    int wave = tid >> 6, lane = tid & 63;
    int jgrp  = blockIdx.x & 255;               // 256 j-groups of 4
    int chunk = blockIdx.x >> 8;                // ISPLIT i-chunks
    int j  = jgrp * 4 + wave;
    int i0 = chunk * ICHUNK;

    const float4* tj = (const float4*)(tmp + (size_t)(j * PAIR_DIM + lane) * DIM_MSA);
    float4 r0 = tj[0], r1 = tj[1], r2 = tj[2], r3 = tj[3],
           r4 = tj[4], r5 = tj[5], r6 = tj[6], r7 = tj[7];
    float bias = b2[lane];

    const size_t stride = (size_t)L_SEQ * PAIR_DIM;              // 65536
    const float* pr = pair + ((size_t)i0 * L_SEQ + j) * PAIR_DIM + lane;
    float*       po = out  + ((size_t)i0 * L_SEQ + j) * PAIR_DIM + lane;

    // prologue: 8 loads in flight
    float pv0 = pr[0 * stride], pv1 = pr[1 * stride],
          pv2 = pr[2 * stride], pv3 = pr[3 * stride],
          pv4 = pr[4 * stride], pv5 = pr[5 * stride],
          pv6 = pr[6 * stride], pv7 = pr[7 * stride];
    pr += (size_t)GRP * stride;

    int ii = i0;

#define STEP(PV) do {                                                         \
        float dv = dot32(s + (size_t)ii * DIM_MSA, r0,r1,r2,r3,r4,r5,r6,r7);  \
        __builtin_nontemporal_store(dv + bias + (PV), po); po += stride;      \
        (PV) = *pr; pr += stride; ++ii;                                       \
    } while (0)

#define STEPL(PV) do {                                                        \
        float dv = dot32(s + (size_t)ii * DIM_MSA, r0,r1,r2,r3,r4,r5,r6,r7);  \
        __builtin_nontemporal_store(dv + bias + (PV), po); po += stride;      \
        ++ii;                                                                 \
    } while (0)

#pragma unroll 1
    for (int g = 0; g < ICHUNK / GRP - 1; ++g) {
        STEP(pv0); STEP(pv1); STEP(pv2); STEP(pv3);
        STEP(pv4); STEP(pv5); STEP(pv6); STEP(pv7);
    }
    // peeled final group: no prefetch (would read past the chunk)
    STEPL(pv0); STEPL(pv1); STEPL(pv2); STEPL(pv3);
    STEPL(pv4); STEPL(pv5); STEPL(pv6); STEPL(pv7);

#undef STEP
#undef STEPL
}

extern "C" void kernel_launch(void* const* d_in, const int* in_sizes, int n_in,
                              void* d_out, int out_size, void* d_ws, size_t ws_size,
                              hipStream_t stream) {
    const float* seq  = (const float*)d_in[0];   // [1,1024,256]
    const float* pair = (const float*)d_in[1];   // [1,1024,1024,64]
    const float* W1   = (const float*)d_in[2];   // [32,256]
    const float* b1   = (const float*)d_in[3];   // [32]
    const float* W2   = (const float*)d_in[4];   // [64,1024]
    const float* b2   = (const float*)d_in[5];   // [64]
    float* out = (float*)d_out;

    float* s_ws   = (float*)d_ws;                         // 1024*32   = 128 KB
    float* tmp_ws = s_ws + (size_t)L_SEQ * DIM_MSA;       // 1024*64*32 = 8 MB

    k_proj1<<<(L_SEQ * DIM_MSA) / 256, 256, 0, stream>>>(seq, W1, b1, s_ws);
    k_proj2<<<(L_SEQ * PAIR_DIM * (DIM_MSA / 4)) / 256, 256, 0, stream>>>(s_ws, W2, tmp_ws);
    k_outer<<<256 * ISPLIT, 256, 0, stream>>>(s_ws, tmp_ws, pair, b2, out);
}